// Round 1
// baseline (1259.175 us; speedup 1.0000x reference)
//
#include <hip/hip_runtime.h>
#include <math.h>

#define BATCH   131072
#define NTHREAD 64

__global__ __launch_bounds__(NTHREAD)
void logicnet_kernel(
    const int*   __restrict__ seq,
    const int*   __restrict__ post,
    const int*   __restrict__ negt,
    const float* __restrict__ E,
    const float* __restrict__ tvec,
    const float* __restrict__ nW1, const float* __restrict__ nb1,
    const float* __restrict__ nW2, const float* __restrict__ nb2,
    const float* __restrict__ aW1, const float* __restrict__ ab1,
    const float* __restrict__ aW2, const float* __restrict__ ab2,
    const float* __restrict__ oW1, const float* __restrict__ ob1,
    const float* __restrict__ oW2, const float* __restrict__ ob2,
    float*       __restrict__ out)
{
    // Per-thread LDS: slot S0 (current input vector) + slot S1 (persisted vector).
    // 64 thr * 128 floats * 4 B = 32 KiB/block -> 5 blocks/CU.
    __shared__ float sh[NTHREAD * 128];
    const int tid = threadIdx.x;
    const int row = blockIdx.x * NTHREAD + tid;
    const int sw  = tid & 31;                 // XOR swizzle -> conflict-free, no padding
    float* const S0 = &sh[tid * 128];
    float* const S1 = S0 + 64;

    float acc[64];

    // ||true_vec|| (uniform, cheap)
    float tn2 = 0.f;
#pragma unroll
    for (int j = 0; j < 64; ++j) tn2 = fmaf(tvec[j], tvec[j], tn2);
    const float tn = fmaxf(sqrtf(tn2), 1e-8f);

    const int i0 = seq[row*5+0];
    const int i1 = seq[row*5+1];
    const int i2 = seq[row*5+2];
    const int i3 = seq[row*5+3];
    const int i4 = seq[row*5+4];
    const int ip = post[row];
    const int im = negt[row];

    auto gather = [&](int idx, float* xs) {
        const float4* e = (const float4*)(E + (size_t)idx * 64);
#pragma unroll
        for (int q = 0; q < 16; ++q) {
            float4 v = e[q];
            xs[(4*q+0) ^ sw] = v.x;
            xs[(4*q+1) ^ sw] = v.y;
            xs[(4*q+2) ^ sw] = v.z;
            xs[(4*q+3) ^ sw] = v.w;
        }
    };
    auto initb = [&](const float* __restrict__ b) {
#pragma unroll
        for (int j = 0; j < 64; ++j) acc[j] = b[j];      // uniform -> SGPR
    };
    // acc[j] += sum_k xs[k] * W[k*64+j]   (one 64x64 matvec pass)
    auto pass = [&](const float* __restrict__ W, const float* xs) {
#pragma unroll 2
        for (int k = 0; k < 64; ++k) {
            const float xk = xs[k ^ sw];                 // per-lane ds_read_b32
            const float* __restrict__ wr = W + k * 64;   // uniform -> s_load
#pragma unroll
            for (int j = 0; j < 64; ++j) acc[j] = fmaf(xk, wr[j], acc[j]);
        }
    };
    auto store_act = [&](float* xs) {                    // leaky_relu(acc) -> LDS
#pragma unroll
        for (int j = 0; j < 64; ++j) {
            float v = acc[j];
            v = (v >= 0.f) ? v : 0.01f * v;
            xs[j ^ sw] = v;
        }
    };
    auto store_raw = [&](float* xs) {
#pragma unroll
        for (int j = 0; j < 64; ++j) xs[j ^ sw] = acc[j];
    };
    auto load_acc = [&](const float* xs) {
#pragma unroll
        for (int j = 0; j < 64; ++j) acc[j] = xs[j ^ sw];
    };
    auto reduce = [&](float* dst) {
        float num = 0.f, ss = 0.f;
#pragma unroll
        for (int j = 0; j < 64; ++j) {
            num = fmaf(acc[j], tvec[j], num);
            ss  = fmaf(acc[j], acc[j], ss);
        }
        const float nrm = fmaxf(sqrtf(ss), 1e-8f);
        *dst = num / (nrm * tn) * 10.0f;
    };

    // ---- i6 = OR(e2 || e3) ----
    gather(i2, S0);
    initb(ob1); pass(oW1, S0);
    gather(i3, S0); pass(oW1 + 64*64, S0);
    store_act(S0); initb(ob2); pass(oW2, S0);
    store_raw(S1);                                   // S1 = i6 (persist)

    // ---- n1 = NOT(e1) ----
    gather(i1, S0);
    initb(nb1); pass(nW1, S0);
    store_act(S0); initb(nb2); pass(nW2, S0);
    store_raw(S0);                                   // S0 = n1

    // ---- i5 = AND(e0 || n1) ----
    initb(ab1); pass(aW1 + 64*64, S0);               // n1 is second input
    gather(i0, S0); pass(aW1, S0);                   // e0 is first input
    store_act(S0); initb(ab2); pass(aW2, S0);
    store_raw(S0);                                   // S0 = i5

    // ---- i7 = AND(i5 || i6) ----
    initb(ab1); pass(aW1, S0); pass(aW1 + 64*64, S1);
    store_act(S0); initb(ab2); pass(aW2, S0);
    store_raw(S0);                                   // S0 = i7

    // ---- n7 = NOT(i7) ----
    initb(nb1); pass(nW1, S0);
    store_act(S0); initb(nb2); pass(nW2, S0);
    store_raw(S0);                                   // S0 = n7

    // ---- out8 = OR(n7 || e4) ----
    initb(ob1); pass(oW1, S0);
    gather(i4, S0); pass(oW1 + 64*64, S0);
    store_act(S0); initb(ob2); pass(oW2, S0);
    store_raw(S0);                                   // S0 = out8

    // ---- enc = NOT(out8) ----
    initb(nb1); pass(nW1, S0);
    store_act(S0); initb(nb2); pass(nW2, S0);
    store_raw(S0);                                   // S0 = enc

    // ---- shared first-half partial: accE = ob1 + enc @ oW1[0:64] ----
    initb(ob1); pass(oW1, S0);
    store_raw(S1);                                   // S1 = accE (i6 dead)

    // ---- encoded_pos = OR(enc || pos_e) ----
    gather(ip, S0); pass(oW1 + 64*64, S0);
    store_act(S0); initb(ob2); pass(oW2, S0);
    reduce(out + row);

    // ---- encoded_neg = OR(enc || neg_e) ----
    load_acc(S1);
    gather(im, S0); pass(oW1 + 64*64, S0);
    store_act(S0); initb(ob2); pass(oW2, S0);
    reduce(out + BATCH + row);
}

extern "C" void kernel_launch(void* const* d_in, const int* in_sizes, int n_in,
                              void* d_out, int out_size, void* d_ws, size_t ws_size,
                              hipStream_t stream) {
    const int*   seq  = (const int*)  d_in[0];
    const int*   post = (const int*)  d_in[1];
    const int*   negt = (const int*)  d_in[2];
    const float* E    = (const float*)d_in[3];
    const float* tv   = (const float*)d_in[4];
    const float* nW1  = (const float*)d_in[5];
    const float* nb1  = (const float*)d_in[6];
    const float* nW2  = (const float*)d_in[7];
    const float* nb2  = (const float*)d_in[8];
    const float* aW1  = (const float*)d_in[9];
    const float* ab1  = (const float*)d_in[10];
    const float* aW2  = (const float*)d_in[11];
    const float* ab2  = (const float*)d_in[12];
    const float* oW1  = (const float*)d_in[13];
    const float* ob1  = (const float*)d_in[14];
    const float* oW2  = (const float*)d_in[15];
    const float* ob2  = (const float*)d_in[16];
    float* out = (float*)d_out;

    dim3 grid(BATCH / NTHREAD), block(NTHREAD);
    hipLaunchKernelGGL(logicnet_kernel, grid, block, 0, stream,
                       seq, post, negt, E, tv,
                       nW1, nb1, nW2, nb2,
                       aW1, ab1, aW2, ab2,
                       oW1, ob1, oW2, ob2, out);
}

// Round 2
// 486.284 us; speedup vs baseline: 2.5894x; 2.5894x over previous
//
#include <hip/hip_runtime.h>
#include <stdint.h>
#include <math.h>

#define BATCH 131072

typedef __attribute__((ext_vector_type(8)))  short short8;   // 8 bf16 = 4 VGPRs
typedef __attribute__((ext_vector_type(16))) float float16;  // MFMA 32x32 acc

#define WS_LO_OFF 65536
#define WS_TN_OFF 131072

// ---------------- prep: split weights fp32 -> bf16 hi/lo in B-fragment order ----------------
// B-frag for mfma_f32_32x32x16_bf16: lane n'=lane&31 -> n = nt*32+n'; k = kc*16 + (lane>>5)*8 + j.
// ws layout: hi: u*8192 + (kc*2+nt)*1024 + lane*16 + j*2 ; lo at +WS_LO_OFF. u in 0..7:
// 0=nW1 1=nW2 2=aW1[0:64] 3=aW1[64:128] 4=aW2 5=oW1[0:64] 6=oW1[64:128] 7=oW2
__global__ __launch_bounds__(256)
void prep_kernel(const float* __restrict__ tvec,
                 const float* __restrict__ nW1, const float* __restrict__ nW2,
                 const float* __restrict__ aW1, const float* __restrict__ aW2,
                 const float* __restrict__ oW1, const float* __restrict__ oW2,
                 char* __restrict__ ws)
{
    const int id = blockIdx.x * 256 + threadIdx.x;
    if (id == 0) {
        float s = 0.f;
        for (int j = 0; j < 64; ++j) s = fmaf(tvec[j], tvec[j], s);
        *(float*)(ws + WS_TN_OFF) = fmaxf(sqrtf(s), 1e-8f);
    }
    const float* srcs[8] = { nW1, nW2, aW1, aW1 + 4096, aW2, oW1, oW1 + 4096, oW2 };
    const int u    = id >> 12;
    const int e    = id & 4095;
    const int j    = e & 7;
    const int lane = (e >> 3) & 63;
    const int f    = e >> 9;          // kc*2 + nt
    const int nt   = f & 1, kc = f >> 1;
    const int k    = kc * 16 + (lane >> 5) * 8 + j;
    const int n    = nt * 32 + (lane & 31);
    const float v  = srcs[u][k * 64 + n];
    const uint32_t b  = __float_as_uint(v);
    const uint32_t hb = b & 0xffff0000u;
    const uint32_t lo = __float_as_uint(v - __uint_as_float(hb));
    ((uint16_t*)(ws + u * 8192 + f * 1024 + lane * 16))[j]             = (uint16_t)(b  >> 16);
    ((uint16_t*)(ws + WS_LO_OFF + u * 8192 + f * 1024 + lane * 16))[j] = (uint16_t)(lo >> 16);
}

// ---------------- main kernel ----------------
union S8 { short8 s; uint32_t u[4]; };
union F8 { float f[8]; uint32_t u[8]; float4 v4[2]; };

struct Frag { short8 hi[4]; short8 lo[4]; };   // A-operand, kc = 0..3 (K=64)

__global__ __launch_bounds__(256)
void logicnet_mfma(const int* __restrict__ seq, const int* __restrict__ post,
                   const int* __restrict__ negt, const float* __restrict__ E,
                   const float* __restrict__ tvec,
                   const float* __restrict__ nb1, const float* __restrict__ nb2,
                   const float* __restrict__ ab1, const float* __restrict__ ab2,
                   const float* __restrict__ ob1, const float* __restrict__ ob2,
                   const char* __restrict__ ws, float* __restrict__ out)
{
    // per-wave private staging: 32 rows x stride 66 u32 (packed hi|lo or raw f32)
    __shared__ uint32_t lds[4 * 2112];
    const int tid  = threadIdx.x;
    const int wid  = tid >> 6;
    const int lane = tid & 63;
    const int m    = lane & 31;     // A row / C col / B col
    const int h    = lane >> 5;     // k-half selector
    const int tile = blockIdx.x * 4 + wid;
    const int rowbase = tile * 32;
    uint32_t* const stage = &lds[wid * 2112];

    const float tn = *(const float*)(ws + WS_TN_OFF);

    // biases, C-layout broadcast: lane's col c = nt*32 + m
    float nb1v[2] = { nb1[m], nb1[32 + m] };
    float nb2v[2] = { nb2[m], nb2[32 + m] };
    float ab1v[2] = { ab1[m], ab1[32 + m] };
    float ab2v[2] = { ab2[m], ab2[32 + m] };
    float ob1v[2] = { ob1[m], ob1[32 + m] };
    float ob2v[2] = { ob2[m], ob2[32 + m] };

    const int rr = rowbase + m;
    const int s0 = seq[rr * 5 + 0], s1i = seq[rr * 5 + 1], s2 = seq[rr * 5 + 2];
    const int s3 = seq[rr * 5 + 3], s4 = seq[rr * 5 + 4];
    const int ip = post[rr], im = negt[rr];

    float16 acc[2], accE[2];

    auto initacc = [&](const float* bv) {
#pragma unroll
        for (int nt = 0; nt < 2; ++nt)
#pragma unroll
            for (int i = 0; i < 16; ++i) acc[nt][i] = bv[nt];
    };

    // accumulate acc += X(frag) @ W(unit u), bf16x3
    auto ua = [&](const Frag& x, int u) {
        const char* base = ws + u * 8192 + lane * 16;
#pragma unroll
        for (int kc = 0; kc < 4; ++kc) {
#pragma unroll
            for (int nt = 0; nt < 2; ++nt) {
                const int off = (kc * 2 + nt) * 1024;
                short8 whi = *(const short8*)(base + off);
                short8 wlo = *(const short8*)(base + WS_LO_OFF + off);
                acc[nt] = __builtin_amdgcn_mfma_f32_32x32x16_bf16(x.hi[kc], whi, acc[nt], 0, 0, 0);
                acc[nt] = __builtin_amdgcn_mfma_f32_32x32x16_bf16(x.lo[kc], whi, acc[nt], 0, 0, 0);
                acc[nt] = __builtin_amdgcn_mfma_f32_32x32x16_bf16(x.hi[kc], wlo, acc[nt], 0, 0, 0);
            }
        }
    };

    // C-layout epilogue -> packed hi|lo u32 into staging. 32 ds_write_b32, conflict-free.
    auto epi_store = [&](bool lrelu) {
#pragma unroll
        for (int nt = 0; nt < 2; ++nt) {
            const int c = nt * 32 + m;
#pragma unroll
            for (int g = 0; g < 4; ++g)
#pragma unroll
                for (int q = 0; q < 4; ++q) {
                    const int r = q + 8 * g + 4 * h;
                    float v = acc[nt][g * 4 + q];
                    if (lrelu) v = fmaxf(v, 0.01f * v);
                    const uint32_t uu = __float_as_uint(v);
                    const uint32_t hb = uu & 0xffff0000u;
                    const uint32_t lo = __float_as_uint(v - __uint_as_float(hb));
                    stage[r * 66 + c] = hb | (lo >> 16);
                }
        }
    };

    // staging -> A-frags (row m, k = kc*16 + h*8 + j). b64 reads, 2-way (free).
    auto load_frags = [&](Frag& x) {
#pragma unroll
        for (int kc = 0; kc < 4; ++kc) {
            const uint32_t* p = &stage[m * 66 + kc * 16 + h * 8];
            uint32_t w[8];
#pragma unroll
            for (int i = 0; i < 8; ++i) w[i] = p[i];
            S8 hi, lo;
#pragma unroll
            for (int i = 0; i < 4; ++i) {
                hi.u[i] = (w[2 * i] >> 16)      | (w[2 * i + 1] & 0xffff0000u);
                lo.u[i] = (w[2 * i] & 0xffffu)  | (w[2 * i + 1] << 16);
            }
            x.hi[kc] = hi.s; x.lo[kc] = lo.s;
        }
    };

    // embedding gather -> A-frags directly (each lane: row m's floats for its k-half)
    auto gather = [&](int idx, Frag& x) {
        const float4* e = (const float4*)(E + (size_t)idx * 64 + h * 8);
#pragma unroll
        for (int kc = 0; kc < 4; ++kc) {
            F8 xf8;
            xf8.v4[0] = e[kc * 4];
            xf8.v4[1] = e[kc * 4 + 1];
            uint32_t lu[8];
#pragma unroll
            for (int i = 0; i < 8; ++i) {
                const float hf = __uint_as_float(xf8.u[i] & 0xffff0000u);
                lu[i] = __float_as_uint(xf8.f[i] - hf);
            }
            S8 hi, lo;
#pragma unroll
            for (int i = 0; i < 4; ++i) {
                hi.u[i] = (xf8.u[2 * i] >> 16) | (xf8.u[2 * i + 1] & 0xffff0000u);
                lo.u[i] = (lu[2 * i] >> 16)    | (lu[2 * i + 1] & 0xffff0000u);
            }
            x.hi[kc] = hi.s; x.lo[kc] = lo.s;
        }
    };

    // final: cosine vs tvec * 10 -> out rows
    auto epi_reduce = [&](float* outp) {
#pragma unroll
        for (int nt = 0; nt < 2; ++nt) {
            const int c = nt * 32 + m;
#pragma unroll
            for (int g = 0; g < 4; ++g)
#pragma unroll
                for (int q = 0; q < 4; ++q) {
                    const int r = q + 8 * g + 4 * h;
                    stage[r * 66 + c] = __float_as_uint(acc[nt][g * 4 + q]);
                }
        }
        float num = 0.f, ss = 0.f;
        const float* tp = tvec + h * 32;
        const uint32_t* xp = &stage[m * 66 + h * 32];
#pragma unroll
        for (int i = 0; i < 32; i += 2) {
            const float x0 = __uint_as_float(xp[i]);
            const float x1 = __uint_as_float(xp[i + 1]);
            num = fmaf(x0, tp[i], fmaf(x1, tp[i + 1], num));
            ss  = fmaf(x0, x0, fmaf(x1, x1, ss));
        }
        num += __shfl_xor(num, 32, 64);
        ss  += __shfl_xor(ss, 32, 64);
        if (h == 0) outp[m] = num / (fmaxf(sqrtf(ss), 1e-8f) * tn) * 10.0f;
    };

    Frag xf, i6f;

    // ---- i6 = OR(e2 || e3) ----
    gather(s2, xf); initacc(ob1v); ua(xf, 5);
    gather(s3, xf); ua(xf, 6);
    epi_store(true);  load_frags(xf);
    initacc(ob2v); ua(xf, 7);
    epi_store(false); load_frags(i6f);          // keep i6 in registers

    // ---- n1 = NOT(e1) ----
    gather(s1i, xf); initacc(nb1v); ua(xf, 0);
    epi_store(true);  load_frags(xf);
    initacc(nb2v); ua(xf, 1);
    epi_store(false); load_frags(xf);           // xf = n1

    // ---- i5 = AND(e0 || n1) ----
    initacc(ab1v); ua(xf, 3);                   // n1 is second input
    gather(s0, xf); ua(xf, 2);                  // e0 is first input
    epi_store(true);  load_frags(xf);
    initacc(ab2v); ua(xf, 4);
    epi_store(false); load_frags(xf);           // xf = i5

    // ---- i7 = AND(i5 || i6) ----
    initacc(ab1v); ua(xf, 2); ua(i6f, 3);
    epi_store(true);  load_frags(xf);
    initacc(ab2v); ua(xf, 4);
    epi_store(false); load_frags(xf);           // xf = i7

    // ---- n7 = NOT(i7) ----
    initacc(nb1v); ua(xf, 0);
    epi_store(true);  load_frags(xf);
    initacc(nb2v); ua(xf, 1);
    epi_store(false); load_frags(xf);           // xf = n7

    // ---- out8 = OR(n7 || e4) ----
    initacc(ob1v); ua(xf, 5);
    gather(s4, xf); ua(xf, 6);
    epi_store(true);  load_frags(xf);
    initacc(ob2v); ua(xf, 7);
    epi_store(false); load_frags(xf);           // xf = out8

    // ---- enc = NOT(out8) ----
    initacc(nb1v); ua(xf, 0);
    epi_store(true);  load_frags(xf);
    initacc(nb2v); ua(xf, 1);
    epi_store(false); load_frags(xf);           // xf = enc

    // ---- accE = ob1 + enc @ oW1[0:64] (shared partial) ----
    initacc(ob1v); ua(xf, 5);
    accE[0] = acc[0]; accE[1] = acc[1];

    // ---- encoded_pos = OR(enc || pos_e) ----
    gather(ip, xf); ua(xf, 6);
    epi_store(true);  load_frags(xf);
    initacc(ob2v); ua(xf, 7);
    epi_reduce(out + rowbase);

    // ---- encoded_neg = OR(enc || neg_e) ----
    acc[0] = accE[0]; acc[1] = accE[1];
    gather(im, xf); ua(xf, 6);
    epi_store(true);  load_frags(xf);
    initacc(ob2v); ua(xf, 7);
    epi_reduce(out + BATCH + rowbase);
}

extern "C" void kernel_launch(void* const* d_in, const int* in_sizes, int n_in,
                              void* d_out, int out_size, void* d_ws, size_t ws_size,
                              hipStream_t stream) {
    const int*   seq  = (const int*)  d_in[0];
    const int*   post = (const int*)  d_in[1];
    const int*   negt = (const int*)  d_in[2];
    const float* E    = (const float*)d_in[3];
    const float* tv   = (const float*)d_in[4];
    const float* nW1  = (const float*)d_in[5];
    const float* nb1  = (const float*)d_in[6];
    const float* nW2  = (const float*)d_in[7];
    const float* nb2  = (const float*)d_in[8];
    const float* aW1  = (const float*)d_in[9];
    const float* ab1  = (const float*)d_in[10];
    const float* aW2  = (const float*)d_in[11];
    const float* ab2  = (const float*)d_in[12];
    const float* oW1  = (const float*)d_in[13];
    const float* ob1  = (const float*)d_in[14];
    const float* oW2  = (const float*)d_in[15];
    const float* ob2  = (const float*)d_in[16];
    float* out = (float*)d_out;
    char*  ws  = (char*)d_ws;   // needs 131076 bytes

    hipLaunchKernelGGL(prep_kernel, dim3(128), dim3(256), 0, stream,
                       tv, nW1, nW2, aW1, aW2, oW1, oW2, ws);
    hipLaunchKernelGGL(logicnet_mfma, dim3(BATCH / 128), dim3(256), 0, stream,
                       seq, post, negt, E, tv,
                       nb1, nb2, ab1, ab2, ob1, ob2, ws, out);
}